// Round 1
// baseline (2422.229 us; speedup 1.0000x reference)
//
#include <hip/hip_runtime.h>
#include <hip/hip_bf16.h>
#include <math.h>

#define B_    8
#define T_    1024
#define C_    576
#define NH_   9
#define NKV_  3
#define HD_   64
#define KVC_  192
#define NREP_ 3

// ---------------- GEMM: C[M,N] = A[M,K] @ W[K,N] + bias[N] ----------------
// 64x64 tile, 256 threads, 4x4 per thread, BK=16, fp32.
__global__ __launch_bounds__(256) void gemm_bias_kernel(
    const float* __restrict__ A, const float* __restrict__ W,
    const float* __restrict__ bias, float* __restrict__ Cc,
    int M, int K, int N) {
  __shared__ float As[16][68];
  __shared__ float Bs[16][68];
  const int bm = blockIdx.y * 64;
  const int bn = blockIdx.x * 64;
  const int tid = threadIdx.x;
  const int tx = tid & 15;
  const int ty = tid >> 4;
  float acc[4][4] = {};

  for (int k0 = 0; k0 < K; k0 += 16) {
    #pragma unroll
    for (int i = 0; i < 4; i++) {
      int idx = tid + i * 256;
      int m = idx >> 4, kk = idx & 15;
      As[kk][m] = A[(size_t)(bm + m) * K + k0 + kk];
    }
    #pragma unroll
    for (int i = 0; i < 4; i++) {
      int idx = tid + i * 256;
      int kk = idx >> 6, n = idx & 63;
      Bs[kk][n] = W[(size_t)(k0 + kk) * N + bn + n];
    }
    __syncthreads();
    #pragma unroll
    for (int kk = 0; kk < 16; kk++) {
      float4 a4 = *(const float4*)&As[kk][ty * 4];
      float4 b4 = *(const float4*)&Bs[kk][tx * 4];
      acc[0][0] += a4.x * b4.x; acc[0][1] += a4.x * b4.y;
      acc[0][2] += a4.x * b4.z; acc[0][3] += a4.x * b4.w;
      acc[1][0] += a4.y * b4.x; acc[1][1] += a4.y * b4.y;
      acc[1][2] += a4.y * b4.z; acc[1][3] += a4.y * b4.w;
      acc[2][0] += a4.z * b4.x; acc[2][1] += a4.z * b4.y;
      acc[2][2] += a4.z * b4.z; acc[2][3] += a4.z * b4.w;
      acc[3][0] += a4.w * b4.x; acc[3][1] += a4.w * b4.y;
      acc[3][2] += a4.w * b4.z; acc[3][3] += a4.w * b4.w;
    }
    __syncthreads();
  }
  #pragma unroll
  for (int i = 0; i < 4; i++) {
    int m = bm + ty * 4 + i;
    #pragma unroll
    for (int j = 0; j < 4; j++) {
      int n = bn + tx * 4 + j;
      Cc[(size_t)m * N + n] = acc[i][j] + bias[n];
    }
  }
}

// ---------------- Causal GQA flash attention (fp32) ----------------
// grid: (T/64, NH, B), block: 256 threads = 4 waves, each wave owns 16 q-rows.
// q: [B*T, C] col h*64+d ; k,v: [B*T, KVC] col kvh*64+d ; y: [B*T, C]
__global__ __launch_bounds__(256) void attn_fwd_kernel(
    const float* __restrict__ q, const float* __restrict__ k,
    const float* __restrict__ v, float* __restrict__ y) {
  const int qt = blockIdx.x;
  const int h  = blockIdx.y;
  const int b  = blockIdx.z;
  const int kvh = h / NREP_;
  const int tid = threadIdx.x;
  const int wave = tid >> 6;
  const int lane = tid & 63;
  const int w16 = wave * 16;
  const int qrow0 = qt * 64;

  __shared__ float q_lds[64][68];
  __shared__ float k_lds[64][68];
  __shared__ float v_lds[64][68];

  const size_t qbase = ((size_t)b * T_ + qrow0) * C_ + h * HD_;
  #pragma unroll
  for (int i = 0; i < 16; i++) {
    int idx = tid + i * 256;
    int r = idx >> 6, d = idx & 63;
    q_lds[r][d] = q[qbase + (size_t)r * C_ + d];
  }

  float m_i[16], l_i[16], o[16];
  #pragma unroll
  for (int r = 0; r < 16; r++) { m_i[r] = -INFINITY; l_i[r] = 0.f; o[r] = 0.f; }

  for (int jt = 0; jt <= qt; jt++) {
    __syncthreads();  // previous-iter LDS readers done (also covers q_lds load at jt=0)
    const size_t kbase = ((size_t)b * T_ + jt * 64) * KVC_ + kvh * HD_;
    #pragma unroll
    for (int i = 0; i < 16; i++) {
      int idx = tid + i * 256;
      int r = idx >> 6, d = idx & 63;
      k_lds[r][d] = k[kbase + (size_t)r * KVC_ + d];
      v_lds[r][d] = v[kbase + (size_t)r * KVC_ + d];
    }
    __syncthreads();

    // scores: sc[r] = q_row(w16+r) . k_key(lane)
    float sc[16];
    #pragma unroll
    for (int r = 0; r < 16; r++) sc[r] = 0.f;
    #pragma unroll
    for (int d4 = 0; d4 < 16; d4++) {
      float4 k4 = *(const float4*)&k_lds[lane][d4 * 4];
      #pragma unroll
      for (int r = 0; r < 16; r++) {
        float4 q4 = *(const float4*)&q_lds[w16 + r][d4 * 4];
        sc[r] += q4.x * k4.x + q4.y * k4.y + q4.z * k4.z + q4.w * k4.w;
      }
    }

    // online softmax per row
    float p[16];
    const int kj = jt * 64 + lane;
    #pragma unroll
    for (int r = 0; r < 16; r++) {
      const int qr = qrow0 + w16 + r;
      float s = (kj <= qr) ? sc[r] * 0.125f : -INFINITY;
      float tm = s;
      #pragma unroll
      for (int off = 32; off > 0; off >>= 1) tm = fmaxf(tm, __shfl_xor(tm, off));
      float mn = fmaxf(m_i[r], tm);
      float alpha = __expf(m_i[r] - mn);   // m_i=-inf on first tile -> alpha=0
      float pv = __expf(s - mn);           // masked lanes: s=-inf -> pv=0
      float ts = pv;
      #pragma unroll
      for (int off = 32; off > 0; off >>= 1) ts += __shfl_xor(ts, off);
      l_i[r] = l_i[r] * alpha + ts;
      m_i[r] = mn;
      o[r] *= alpha;
      p[r] = pv;
    }

    // PV: o[r][lane] += sum_j p[r][j] * v[j][lane]
    #pragma unroll
    for (int j = 0; j < 64; j++) {
      float vj = v_lds[j][lane];
      #pragma unroll
      for (int r = 0; r < 16; r++) {
        o[r] += __shfl(p[r], j) * vj;   // compile-time j -> readlane broadcast
      }
    }
  }

  const size_t ybase = ((size_t)b * T_ + qrow0 + w16) * C_ + h * HD_;
  #pragma unroll
  for (int r = 0; r < 16; r++) {
    y[ybase + (size_t)r * C_ + lane] = o[r] / l_i[r];
  }
}

extern "C" void kernel_launch(void* const* d_in, const int* in_sizes, int n_in,
                              void* d_out, int out_size, void* d_ws, size_t ws_size,
                              hipStream_t stream) {
  const float* x  = (const float*)d_in[0];
  const float* Wq = (const float*)d_in[1];
  const float* bq = (const float*)d_in[2];
  const float* Wk = (const float*)d_in[3];
  const float* bk = (const float*)d_in[4];
  const float* Wv = (const float*)d_in[5];
  const float* bv = (const float*)d_in[6];
  const float* Wo = (const float*)d_in[7];
  const float* bo = (const float*)d_in[8];
  float* out = (float*)d_out;

  const int M = B_ * T_;  // 8192
  float* q = (float*)d_ws;
  float* kk = q + (size_t)M * C_;
  float* vv = kk + (size_t)M * KVC_;
  float* y  = vv + (size_t)M * KVC_;

  dim3 blk(256);
  // Q projection: [8192,576] = x @ Wq + bq
  gemm_bias_kernel<<<dim3(C_ / 64, M / 64), blk, 0, stream>>>(x, Wq, bq, q, M, C_, C_);
  // K projection: [8192,192]
  gemm_bias_kernel<<<dim3(KVC_ / 64, M / 64), blk, 0, stream>>>(x, Wk, bk, kk, M, C_, KVC_);
  // V projection
  gemm_bias_kernel<<<dim3(KVC_ / 64, M / 64), blk, 0, stream>>>(x, Wv, bv, vv, M, C_, KVC_);
  // attention
  attn_fwd_kernel<<<dim3(T_ / 64, NH_, B_), blk, 0, stream>>>(q, kk, vv, y);
  // output projection: out = y @ Wo + bo
  gemm_bias_kernel<<<dim3(C_ / 64, M / 64), blk, 0, stream>>>(y, Wo, bo, out, M, C_, C_);
}

// Round 2
// 353.159 us; speedup vs baseline: 6.8588x; 6.8588x over previous
//
#include <hip/hip_runtime.h>
#include <hip/hip_bf16.h>
#include <math.h>

#define B_    8
#define T_    1024
#define C_    576
#define NH_   9
#define NKV_  3
#define HD_   64
#define KVC_  192
#define NREP_ 3

typedef __attribute__((ext_vector_type(8))) short bf16x8;
typedef __attribute__((ext_vector_type(4))) float f32x4;
typedef __attribute__((ext_vector_type(4))) int i32x4;

#define MFMA_16x16x32(a, b, c) __builtin_amdgcn_mfma_f32_16x16x32_bf16((a), (b), (c), 0, 0, 0)

__device__ __forceinline__ ushort f2bf(float f) {
  __hip_bfloat16 h = __float2bfloat16(f);
  return *reinterpret_cast<const ushort*>(&h);
}

// swizzled ushort-index into a row-stride-64 bf16 LDS tile (XOR bank swizzle, G4)
__device__ __forceinline__ int swz(int row, int col) {
  int byte = (row << 7) + (col << 1);
  return (byte ^ ((row & 7) << 4)) >> 1;
}

// 8 consecutive fp32 -> packed 8x bf16 (16B)
__device__ __forceinline__ i32x4 packrow(const float* src) {
  const float4 a = *reinterpret_cast<const float4*>(src);
  const float4 b = *reinterpret_cast<const float4*>(src + 4);
  union { ushort u[8]; i32x4 v; } t;
  t.u[0] = f2bf(a.x); t.u[1] = f2bf(a.y); t.u[2] = f2bf(a.z); t.u[3] = f2bf(a.w);
  t.u[4] = f2bf(b.x); t.u[5] = f2bf(b.y); t.u[6] = f2bf(b.z); t.u[7] = f2bf(b.w);
  return t.v;
}

// ---------------- GEMM: C[M,N] = A[M,K] @ W[K,N] + bias[N] (fp32) ----------------
__global__ __launch_bounds__(256) void gemm_bias_kernel(
    const float* __restrict__ A, const float* __restrict__ W,
    const float* __restrict__ bias, float* __restrict__ Cc,
    int M, int K, int N) {
  __shared__ float As[16][68];
  __shared__ float Bs[16][68];
  const int bm = blockIdx.y * 64;
  const int bn = blockIdx.x * 64;
  const int tid = threadIdx.x;
  const int tx = tid & 15;
  const int ty = tid >> 4;
  float acc[4][4] = {};

  for (int k0 = 0; k0 < K; k0 += 16) {
    #pragma unroll
    for (int i = 0; i < 4; i++) {
      int idx = tid + i * 256;
      int m = idx >> 4, kk = idx & 15;
      As[kk][m] = A[(size_t)(bm + m) * K + k0 + kk];
    }
    #pragma unroll
    for (int i = 0; i < 4; i++) {
      int idx = tid + i * 256;
      int kk = idx >> 6, n = idx & 63;
      Bs[kk][n] = W[(size_t)(k0 + kk) * N + bn + n];
    }
    __syncthreads();
    #pragma unroll
    for (int kk = 0; kk < 16; kk++) {
      float4 a4 = *(const float4*)&As[kk][ty * 4];
      float4 b4 = *(const float4*)&Bs[kk][tx * 4];
      acc[0][0] += a4.x * b4.x; acc[0][1] += a4.x * b4.y;
      acc[0][2] += a4.x * b4.z; acc[0][3] += a4.x * b4.w;
      acc[1][0] += a4.y * b4.x; acc[1][1] += a4.y * b4.y;
      acc[1][2] += a4.y * b4.z; acc[1][3] += a4.y * b4.w;
      acc[2][0] += a4.z * b4.x; acc[2][1] += a4.z * b4.y;
      acc[2][2] += a4.z * b4.z; acc[2][3] += a4.z * b4.w;
      acc[3][0] += a4.w * b4.x; acc[3][1] += a4.w * b4.y;
      acc[3][2] += a4.w * b4.z; acc[3][3] += a4.w * b4.w;
    }
    __syncthreads();
  }
  #pragma unroll
  for (int i = 0; i < 4; i++) {
    int m = bm + ty * 4 + i;
    #pragma unroll
    for (int j = 0; j < 4; j++) {
      int n = bn + tx * 4 + j;
      Cc[(size_t)m * N + n] = acc[i][j] + bias[n];
    }
  }
}

// ---------------- Causal GQA flash attention, bf16 MFMA ----------------
// grid (T/64, NH, B), 256 threads = 4 waves; wave w owns q-rows w*16..w*16+15.
__global__ __launch_bounds__(256) void attn_mfma_kernel(
    const float* __restrict__ q, const float* __restrict__ k,
    const float* __restrict__ v, float* __restrict__ y) {
  const int qt = blockIdx.x, h = blockIdx.y, b = blockIdx.z;
  const int kvh = h / NREP_;
  const int tid = threadIdx.x;
  const int wave = tid >> 6, lane = tid & 63;
  const int lg = lane >> 4, ll = lane & 15;
  const int w16 = wave << 4;
  const int qrow0 = qt << 6;

  __shared__ ushort Qs[64 * 64];
  __shared__ ushort Ks[64 * 64];
  __shared__ ushort Vts[64 * 64];   // Vts[d][key]
  __shared__ ushort Ps[4][16 * 64]; // per-wave P staging

  // ---- stage Q tile (each wave stages exactly its own 16 rows)
  {
    const int r = tid >> 2, cb = (tid & 3) << 4;
    const float* src = q + (size_t)(b * T_ + qrow0 + r) * C_ + h * HD_ + cb;
    *reinterpret_cast<i32x4*>(&Qs[swz(r, cb)])     = packrow(src);
    *reinterpret_cast<i32x4*>(&Qs[swz(r, cb + 8)]) = packrow(src + 8);
  }
  // Q A-fragments (in-wave LDS ordering suffices: own wave staged own rows)
  const bf16x8 qa0 = *reinterpret_cast<const bf16x8*>(&Qs[swz(w16 + ll, lg * 8)]);
  const bf16x8 qa1 = *reinterpret_cast<const bf16x8*>(&Qs[swz(w16 + ll, 32 + lg * 8)]);

  f32x4 o[4] = {};  // o[d0][r]: O[w16 + lg*4 + r][d0*16 + ll]
  float m_i[4] = {-INFINITY, -INFINITY, -INFINITY, -INFINITY};
  float l_i[4] = {0.f, 0.f, 0.f, 0.f};

  for (int jt = 0; jt <= qt; jt++) {
    __syncthreads();  // all waves done reading previous K/V tile
    {
      // K: row-major bf16
      const int r = tid >> 2, cb = (tid & 3) << 4;
      const float* ksrc = k + (size_t)(b * T_ + (jt << 6) + r) * KVC_ + kvh * HD_ + cb;
      *reinterpret_cast<i32x4*>(&Ks[swz(r, cb)])     = packrow(ksrc);
      *reinterpret_cast<i32x4*>(&Ks[swz(r, cb + 8)]) = packrow(ksrc + 8);
      // V: transposed into Vts[d][key]
      const int vkey = tid & 63, db = (tid >> 6) << 4;
      const float* vsrc = v + (size_t)(b * T_ + (jt << 6) + vkey) * KVC_ + kvh * HD_ + db;
      #pragma unroll
      for (int e = 0; e < 16; e += 4) {
        const float4 vv = *reinterpret_cast<const float4*>(vsrc + e);
        Vts[swz(db + e,     vkey)] = f2bf(vv.x);
        Vts[swz(db + e + 1, vkey)] = f2bf(vv.y);
        Vts[swz(db + e + 2, vkey)] = f2bf(vv.z);
        Vts[swz(db + e + 3, vkey)] = f2bf(vv.w);
      }
    }
    __syncthreads();

    // ---- S = Q K^T : wave computes 16 q-rows x 64 keys (8 MFMA)
    f32x4 s[4] = {};
    #pragma unroll
    for (int kc = 0; kc < 4; kc++) {
      const bf16x8 kb0 = *reinterpret_cast<const bf16x8*>(&Ks[swz(kc * 16 + ll, lg * 8)]);
      const bf16x8 kb1 = *reinterpret_cast<const bf16x8*>(&Ks[swz(kc * 16 + ll, 32 + lg * 8)]);
      s[kc] = MFMA_16x16x32(qa0, kb0, s[kc]);
      s[kc] = MFMA_16x16x32(qa1, kb1, s[kc]);
    }

    // ---- online softmax; lane holds S[w16+lg*4+r][jt*64 + kc*16 + ll]
    const bool diag = (jt == qt);
    #pragma unroll
    for (int kc = 0; kc < 4; kc++) {
      #pragma unroll
      for (int r = 0; r < 4; r++) {
        float val = s[kc][r] * 0.125f;   // 1/sqrt(64)
        if (diag && (kc * 16 + ll > w16 + lg * 4 + r)) val = -INFINITY;
        s[kc][r] = val;
      }
    }
    float al[4];
    #pragma unroll
    for (int r = 0; r < 4; r++) {
      float t0 = fmaxf(fmaxf(s[0][r], s[1][r]), fmaxf(s[2][r], s[3][r]));
      t0 = fmaxf(t0, __shfl_xor(t0, 1));
      t0 = fmaxf(t0, __shfl_xor(t0, 2));
      t0 = fmaxf(t0, __shfl_xor(t0, 4));
      t0 = fmaxf(t0, __shfl_xor(t0, 8));
      const float mn = fmaxf(m_i[r], t0);
      al[r] = __expf(m_i[r] - mn);
      m_i[r] = mn;
    }
    ushort* Pw = Ps[wave];
    #pragma unroll
    for (int r = 0; r < 4; r++) {
      float rs = 0.f;
      #pragma unroll
      for (int kc = 0; kc < 4; kc++) {
        const float p = __expf(s[kc][r] - m_i[r]);
        s[kc][r] = p;
        rs += p;
        Pw[swz(lg * 4 + r, kc * 16 + ll)] = f2bf(p);
      }
      rs += __shfl_xor(rs, 1);
      rs += __shfl_xor(rs, 2);
      rs += __shfl_xor(rs, 4);
      rs += __shfl_xor(rs, 8);
      l_i[r] = l_i[r] * al[r] + rs;
      o[0][r] *= al[r]; o[1][r] *= al[r]; o[2][r] *= al[r]; o[3][r] *= al[r];
    }

    // ---- O += P V  (8 MFMA; same k-convention for A and B fragments)
    #pragma unroll
    for (int kh = 0; kh < 2; kh++) {
      const bf16x8 pa = *reinterpret_cast<const bf16x8*>(&Pw[swz(ll, kh * 32 + lg * 8)]);
      #pragma unroll
      for (int d0 = 0; d0 < 4; d0++) {
        const bf16x8 vb = *reinterpret_cast<const bf16x8*>(&Vts[swz(d0 * 16 + ll, kh * 32 + lg * 8)]);
        o[d0] = MFMA_16x16x32(pa, vb, o[d0]);
      }
    }
  }

  // ---- epilogue
  const size_t ybase = (size_t)(b * T_ + qrow0 + w16) * C_ + h * HD_;
  #pragma unroll
  for (int r = 0; r < 4; r++) {
    const float inv = 1.f / l_i[r];
    #pragma unroll
    for (int d0 = 0; d0 < 4; d0++) {
      y[ybase + (size_t)(lg * 4 + r) * C_ + d0 * 16 + ll] = o[d0][r] * inv;
    }
  }
}

extern "C" void kernel_launch(void* const* d_in, const int* in_sizes, int n_in,
                              void* d_out, int out_size, void* d_ws, size_t ws_size,
                              hipStream_t stream) {
  const float* x  = (const float*)d_in[0];
  const float* Wq = (const float*)d_in[1];
  const float* bq = (const float*)d_in[2];
  const float* Wk = (const float*)d_in[3];
  const float* bk = (const float*)d_in[4];
  const float* Wv = (const float*)d_in[5];
  const float* bv = (const float*)d_in[6];
  const float* Wo = (const float*)d_in[7];
  const float* bo = (const float*)d_in[8];
  float* out = (float*)d_out;

  const int M = B_ * T_;  // 8192
  float* q  = (float*)d_ws;
  float* kk = q + (size_t)M * C_;
  float* vv = kk + (size_t)M * KVC_;
  float* y  = vv + (size_t)M * KVC_;

  dim3 blk(256);
  gemm_bias_kernel<<<dim3(C_ / 64, M / 64), blk, 0, stream>>>(x, Wq, bq, q, M, C_, C_);
  gemm_bias_kernel<<<dim3(KVC_ / 64, M / 64), blk, 0, stream>>>(x, Wk, bk, kk, M, C_, KVC_);
  gemm_bias_kernel<<<dim3(KVC_ / 64, M / 64), blk, 0, stream>>>(x, Wv, bv, vv, M, C_, KVC_);
  attn_mfma_kernel<<<dim3(T_ / 64, NH_, B_), blk, 0, stream>>>(q, kk, vv, y);
  gemm_bias_kernel<<<dim3(C_ / 64, M / 64), blk, 0, stream>>>(y, Wo, bo, out, M, C_, C_);
}

// Round 3
// 132.835 us; speedup vs baseline: 18.2349x; 2.6586x over previous
//
#include <hip/hip_runtime.h>
#include <hip/hip_bf16.h>
#include <math.h>

#define B_    8
#define T_    1024
#define C_    576
#define NH_   9
#define NKV_  3
#define HD_   64
#define KVC_  192
#define NREP_ 3
#define NQKV_ 960   // 576 + 192 + 192

typedef __attribute__((ext_vector_type(8))) short bf16x8;
typedef __attribute__((ext_vector_type(4))) float f32x4;
typedef __attribute__((ext_vector_type(4))) int i32x4;

#define MFMA_16x16x32(a, b, c) __builtin_amdgcn_mfma_f32_16x16x32_bf16((a), (b), (c), 0, 0, 0)

__device__ __forceinline__ ushort f2bf(float f) {
  __hip_bfloat16 h = __float2bfloat16(f);
  return *reinterpret_cast<const ushort*>(&h);
}

// swizzled ushort-index into a row-stride-64(bf16) LDS tile (XOR bank swizzle)
__device__ __forceinline__ int swz(int row, int col) {
  int byte = (row << 7) + (col << 1);
  return (byte ^ ((row & 7) << 4)) >> 1;
}

// 8 consecutive fp32 -> packed 8x bf16 (16B)
__device__ __forceinline__ i32x4 packrow(const float* src) {
  const float4 a = *reinterpret_cast<const float4*>(src);
  const float4 b = *reinterpret_cast<const float4*>(src + 4);
  union { ushort u[8]; i32x4 v; } t;
  t.u[0] = f2bf(a.x); t.u[1] = f2bf(a.y); t.u[2] = f2bf(a.z); t.u[3] = f2bf(a.w);
  t.u[4] = f2bf(b.x); t.u[5] = f2bf(b.y); t.u[6] = f2bf(b.z); t.u[7] = f2bf(b.w);
  return t.v;
}

// ---------------- weight convert+transpose: Wt[n][k] bf16, bias concat ----------------
// grid (6, 72), block 256. n = bx*256+tid in [0,1536), k8 = by in [0,72).
__global__ __launch_bounds__(256) void convert_w_kernel(
    const float* __restrict__ Wq, const float* __restrict__ Wk,
    const float* __restrict__ Wv, const float* __restrict__ Wo,
    const float* __restrict__ bq, const float* __restrict__ bk,
    const float* __restrict__ bv, const float* __restrict__ bo,
    ushort* __restrict__ wqkvT, ushort* __restrict__ woT, float* __restrict__ bcat) {
  const int n = blockIdx.x * 256 + threadIdx.x;
  const int k8 = blockIdx.y;
  const float* src; int ld; ushort* dst;
  if (n < 576)      { src = Wq + n;        ld = C_;  dst = wqkvT + (size_t)n * C_; }
  else if (n < 768) { src = Wk + (n - 576); ld = KVC_; dst = wqkvT + (size_t)n * C_; }
  else if (n < 960) { src = Wv + (n - 768); ld = KVC_; dst = wqkvT + (size_t)n * C_; }
  else              { src = Wo + (n - 960); ld = C_;  dst = woT + (size_t)(n - 960) * C_; }
  union { ushort u[8]; i32x4 v; } t;
  #pragma unroll
  for (int e = 0; e < 8; e++) t.u[e] = f2bf(src[(size_t)(k8 * 8 + e) * ld]);
  *reinterpret_cast<i32x4*>(dst + k8 * 8) = t.v;
  if (k8 == 0) {
    if (n < 576)      bcat[n] = bq[n];
    else if (n < 768) bcat[n] = bk[n - 576];
    else if (n < 960) bcat[n] = bv[n - 768];
    else              bcat[n] = bo[n - 960];
  }
}

// ---------------- bf16 MFMA GEMM: C[M,N] = A[M,K] @ Bt[N,K]^T + bias ----------------
// 128x64 tile, 4 waves (2x2), each wave 64x32 = 4x2 16x16 frags, BK=64.
// A_F32: A is fp32 (converted to bf16 during staging); else bf16.
// OUT_BF16: write bf16, else fp32. Leading q_cols columns scaled by 0.125.
template<bool A_F32, bool OUT_BF16>
__global__ __launch_bounds__(256) void gemm_mfma_kernel(
    const void* __restrict__ Ap, const ushort* __restrict__ Bt,
    const float* __restrict__ bias, void* __restrict__ Cp,
    int M, int K, int N, int q_cols) {
  __shared__ ushort As[128 * 64];
  __shared__ ushort Bs[64 * 64];
  const int bm = blockIdx.y * 128, bn = blockIdx.x * 64;
  const int tid = threadIdx.x;
  const int wave = tid >> 6, lane = tid & 63;
  const int lg = lane >> 4, ll = lane & 15;
  const int wm = (wave >> 1) * 64, wn = (wave & 1) * 32;
  f32x4 acc[4][2] = {};

  for (int k0 = 0; k0 < K; k0 += 64) {
    // stage A tile (128 x 64 bf16): 1024 16B-chunks, 4 per thread
    if (A_F32) {
      const float* A = (const float*)Ap;
      #pragma unroll
      for (int i = 0; i < 4; i++) {
        int c = tid + i * 256;
        int row = c >> 3, colb = (c & 7) * 8;
        *reinterpret_cast<i32x4*>(&As[swz(row, colb)]) =
            packrow(A + (size_t)(bm + row) * K + k0 + colb);
      }
    } else {
      const ushort* A = (const ushort*)Ap;
      #pragma unroll
      for (int i = 0; i < 4; i++) {
        int c = tid + i * 256;
        int row = c >> 3, colb = (c & 7) * 8;
        *reinterpret_cast<i32x4*>(&As[swz(row, colb)]) =
            *reinterpret_cast<const i32x4*>(A + (size_t)(bm + row) * K + k0 + colb);
      }
    }
    // stage Bt tile (64 x 64): 512 chunks, 2 per thread
    #pragma unroll
    for (int i = 0; i < 2; i++) {
      int c = tid + i * 256;
      int row = c >> 3, colb = (c & 7) * 8;
      *reinterpret_cast<i32x4*>(&Bs[swz(row, colb)]) =
          *reinterpret_cast<const i32x4*>(Bt + (size_t)(bn + row) * K + k0 + colb);
    }
    __syncthreads();

    bf16x8 af[4][2], bfr[2][2];
    #pragma unroll
    for (int mt = 0; mt < 4; mt++) {
      af[mt][0] = *reinterpret_cast<const bf16x8*>(&As[swz(wm + mt * 16 + ll, lg * 8)]);
      af[mt][1] = *reinterpret_cast<const bf16x8*>(&As[swz(wm + mt * 16 + ll, 32 + lg * 8)]);
    }
    #pragma unroll
    for (int nt = 0; nt < 2; nt++) {
      bfr[nt][0] = *reinterpret_cast<const bf16x8*>(&Bs[swz(wn + nt * 16 + ll, lg * 8)]);
      bfr[nt][1] = *reinterpret_cast<const bf16x8*>(&Bs[swz(wn + nt * 16 + ll, 32 + lg * 8)]);
    }
    #pragma unroll
    for (int mt = 0; mt < 4; mt++) {
      #pragma unroll
      for (int nt = 0; nt < 2; nt++) {
        acc[mt][nt] = MFMA_16x16x32(af[mt][0], bfr[nt][0], acc[mt][nt]);
        acc[mt][nt] = MFMA_16x16x32(af[mt][1], bfr[nt][1], acc[mt][nt]);
      }
    }
    __syncthreads();
  }

  // epilogue: C/D layout col=lane&15, row=(lane>>4)*4+reg
  #pragma unroll
  for (int mt = 0; mt < 4; mt++) {
    #pragma unroll
    for (int nt = 0; nt < 2; nt++) {
      const int col = bn + wn + nt * 16 + ll;
      const float scale = (col < q_cols) ? 0.125f : 1.0f;
      #pragma unroll
      for (int r = 0; r < 4; r++) {
        const int row = bm + wm + mt * 16 + lg * 4 + r;
        const float val = (acc[mt][nt][r] + bias[col]) * scale;
        if (OUT_BF16) ((ushort*)Cp)[(size_t)row * N + col] = f2bf(val);
        else          ((float*)Cp)[(size_t)row * N + col] = val;
      }
    }
  }
}

// ---------------- Causal GQA flash attention, bf16 MFMA ----------------
// qkv bf16 [B*T][960]: q at h*64 (pre-scaled by 0.125), k at 576+kvh*64, v at 768+kvh*64.
// grid (T/64, NH, B), 256 threads = 4 waves; wave w owns q-rows w*16..w*16+15.
__global__ __launch_bounds__(256) void attn_mfma_kernel(
    const ushort* __restrict__ qkv, ushort* __restrict__ y) {
  const int qt = blockIdx.x, h = blockIdx.y, b = blockIdx.z;
  const int kvh = h / NREP_;
  const int tid = threadIdx.x;
  const int wave = tid >> 6, lane = tid & 63;
  const int lg = lane >> 4, ll = lane & 15;
  const int w16 = wave << 4;
  const int qrow0 = qt << 6;

  __shared__ ushort Ks[64 * 64];
  __shared__ ushort Vts[64 * 64];   // Vts[d][key]
  __shared__ ushort Ps[4][16 * 64]; // per-wave P staging

  // Q A-fragments straight from global (bf16, pre-scaled)
  const ushort* qrow = qkv + (size_t)(b * T_ + qrow0 + w16 + ll) * NQKV_ + h * HD_;
  const bf16x8 qa0 = *reinterpret_cast<const bf16x8*>(qrow + lg * 8);
  const bf16x8 qa1 = *reinterpret_cast<const bf16x8*>(qrow + 32 + lg * 8);

  f32x4 o[4] = {};  // o[d0][r]: O[w16 + lg*4 + r][d0*16 + ll]
  float m_i[4] = {-INFINITY, -INFINITY, -INFINITY, -INFINITY};
  float l_i[4] = {0.f, 0.f, 0.f, 0.f};

  for (int jt = 0; jt <= qt; jt++) {
    __syncthreads();  // previous-iter LDS readers done
    {
      // K: 64 rows x 64 d, 2 chunks/thread
      #pragma unroll
      for (int i = 0; i < 2; i++) {
        int c = tid + i * 256;
        int row = c >> 3, colb = (c & 7) * 8;
        *reinterpret_cast<i32x4*>(&Ks[swz(row, colb)]) =
            *reinterpret_cast<const i32x4*>(
                qkv + (size_t)(b * T_ + (jt << 6) + row) * NQKV_ + 576 + kvh * HD_ + colb);
      }
      // V transposed: Vts[d][key]
      const int vkey = tid & 63, db = (tid >> 6) << 4;
      const ushort* vsrc = qkv + (size_t)(b * T_ + (jt << 6) + vkey) * NQKV_ + 768 + kvh * HD_ + db;
      const bf16x8 v0 = *reinterpret_cast<const bf16x8*>(vsrc);
      const bf16x8 v1 = *reinterpret_cast<const bf16x8*>(vsrc + 8);
      #pragma unroll
      for (int e = 0; e < 8; e++) {
        Vts[swz(db + e, vkey)] = ((ushort)v0[e]);
        Vts[swz(db + 8 + e, vkey)] = ((ushort)v1[e]);
      }
    }
    __syncthreads();

    // ---- S = Q K^T (8 MFMA)
    f32x4 s[4] = {};
    #pragma unroll
    for (int kc = 0; kc < 4; kc++) {
      const bf16x8 kb0 = *reinterpret_cast<const bf16x8*>(&Ks[swz(kc * 16 + ll, lg * 8)]);
      const bf16x8 kb1 = *reinterpret_cast<const bf16x8*>(&Ks[swz(kc * 16 + ll, 32 + lg * 8)]);
      s[kc] = MFMA_16x16x32(qa0, kb0, s[kc]);
      s[kc] = MFMA_16x16x32(qa1, kb1, s[kc]);
    }

    // ---- online softmax; lane holds S[w16+lg*4+r][kc*16+ll] (already scaled)
    const bool diag = (jt == qt);
    if (diag) {
      #pragma unroll
      for (int kc = 0; kc < 4; kc++)
        #pragma unroll
        for (int r = 0; r < 4; r++)
          if (kc * 16 + ll > w16 + lg * 4 + r) s[kc][r] = -INFINITY;
    }
    float al[4];
    #pragma unroll
    for (int r = 0; r < 4; r++) {
      float t0 = fmaxf(fmaxf(s[0][r], s[1][r]), fmaxf(s[2][r], s[3][r]));
      t0 = fmaxf(t0, __shfl_xor(t0, 1));
      t0 = fmaxf(t0, __shfl_xor(t0, 2));
      t0 = fmaxf(t0, __shfl_xor(t0, 4));
      t0 = fmaxf(t0, __shfl_xor(t0, 8));
      const float mn = fmaxf(m_i[r], t0);
      al[r] = __expf(m_i[r] - mn);
      m_i[r] = mn;
    }
    ushort* Pw = Ps[wave];
    #pragma unroll
    for (int r = 0; r < 4; r++) {
      float rs = 0.f;
      #pragma unroll
      for (int kc = 0; kc < 4; kc++) {
        const float p = __expf(s[kc][r] - m_i[r]);
        rs += p;
        Pw[swz(lg * 4 + r, kc * 16 + ll)] = f2bf(p);
      }
      rs += __shfl_xor(rs, 1);
      rs += __shfl_xor(rs, 2);
      rs += __shfl_xor(rs, 4);
      rs += __shfl_xor(rs, 8);
      l_i[r] = l_i[r] * al[r] + rs;
      o[0][r] *= al[r]; o[1][r] *= al[r]; o[2][r] *= al[r]; o[3][r] *= al[r];
    }

    // ---- O += P V (8 MFMA)
    #pragma unroll
    for (int kh = 0; kh < 2; kh++) {
      const bf16x8 pa = *reinterpret_cast<const bf16x8*>(&Pw[swz(ll, kh * 32 + lg * 8)]);
      #pragma unroll
      for (int d0 = 0; d0 < 4; d0++) {
        const bf16x8 vb = *reinterpret_cast<const bf16x8*>(&Vts[swz(d0 * 16 + ll, kh * 32 + lg * 8)]);
        o[d0] = MFMA_16x16x32(pa, vb, o[d0]);
      }
    }
  }

  // ---- epilogue: y bf16
  #pragma unroll
  for (int r = 0; r < 4; r++) {
    const float inv = 1.f / l_i[r];
    ushort* yrow = y + (size_t)(b * T_ + qrow0 + w16 + lg * 4 + r) * C_ + h * HD_;
    #pragma unroll
    for (int d0 = 0; d0 < 4; d0++) {
      yrow[d0 * 16 + ll] = f2bf(o[d0][r] * inv);
    }
  }
}

extern "C" void kernel_launch(void* const* d_in, const int* in_sizes, int n_in,
                              void* d_out, int out_size, void* d_ws, size_t ws_size,
                              hipStream_t stream) {
  const float* x  = (const float*)d_in[0];
  const float* Wq = (const float*)d_in[1];
  const float* bq = (const float*)d_in[2];
  const float* Wk = (const float*)d_in[3];
  const float* bk = (const float*)d_in[4];
  const float* Wv = (const float*)d_in[5];
  const float* bv = (const float*)d_in[6];
  const float* Wo = (const float*)d_in[7];
  const float* bo = (const float*)d_in[8];
  float* out = (float*)d_out;

  const int M = B_ * T_;  // 8192
  // ws layout (all 16B-aligned)
  ushort* wqkvT = (ushort*)d_ws;                      // [960][576]
  ushort* woT   = wqkvT + (size_t)NQKV_ * C_;          // [576][576]
  float*  bcat  = (float*)(woT + (size_t)C_ * C_);     // [1536]
  ushort* qkv   = (ushort*)(bcat + 1536);              // [8192][960]
  ushort* y     = qkv + (size_t)M * NQKV_;             // [8192][576]

  convert_w_kernel<<<dim3(6, 72), 256, 0, stream>>>(Wq, Wk, Wv, Wo, bq, bk, bv, bo,
                                                    wqkvT, woT, bcat);
  gemm_mfma_kernel<true, true><<<dim3(NQKV_ / 64, M / 128), 256, 0, stream>>>(
      x, wqkvT, bcat, qkv, M, C_, NQKV_, 576);
  attn_mfma_kernel<<<dim3(T_ / 64, NH_, B_), 256, 0, stream>>>(qkv, y);
  gemm_mfma_kernel<false, false><<<dim3(C_ / 64, M / 128), 256, 0, stream>>>(
      y, woT, bcat + NQKV_, out, M, C_, C_, 0);
}

// Round 4
// 127.068 us; speedup vs baseline: 19.0625x; 1.0454x over previous
//
#include <hip/hip_runtime.h>
#include <hip/hip_bf16.h>
#include <math.h>

#define B_    8
#define T_    1024
#define C_    576
#define NH_   9
#define NKV_  3
#define HD_   64
#define KVC_  192
#define NREP_ 3
#define NQKV_ 960   // 576 + 192 + 192

typedef __attribute__((ext_vector_type(8))) short bf16x8;
typedef __attribute__((ext_vector_type(4))) float f32x4;
typedef __attribute__((ext_vector_type(4))) int i32x4;

#define MFMA_16x16x32(a, b, c) __builtin_amdgcn_mfma_f32_16x16x32_bf16((a), (b), (c), 0, 0, 0)

__device__ __forceinline__ ushort f2bf(float f) {
  __hip_bfloat16 h = __float2bfloat16(f);
  return *reinterpret_cast<const ushort*>(&h);
}

// swizzled ushort-index into a row-stride-64(bf16) LDS tile (XOR bank swizzle)
__device__ __forceinline__ int swz(int row, int col) {
  int byte = (row << 7) + (col << 1);
  return (byte ^ ((row & 7) << 4)) >> 1;
}

// 8 consecutive fp32 -> packed 8x bf16 (16B)
__device__ __forceinline__ i32x4 packrow(const float* src) {
  const float4 a = *reinterpret_cast<const float4*>(src);
  const float4 b = *reinterpret_cast<const float4*>(src + 4);
  union { ushort u[8]; i32x4 v; } t;
  t.u[0] = f2bf(a.x); t.u[1] = f2bf(a.y); t.u[2] = f2bf(a.z); t.u[3] = f2bf(a.w);
  t.u[4] = f2bf(b.x); t.u[5] = f2bf(b.y); t.u[6] = f2bf(b.z); t.u[7] = f2bf(b.w);
  return t.v;
}

// ---------------- weight convert+transpose: Wt[n][k] bf16, bias concat ----------------
__global__ __launch_bounds__(256) void convert_w_kernel(
    const float* __restrict__ Wq, const float* __restrict__ Wk,
    const float* __restrict__ Wv, const float* __restrict__ Wo,
    const float* __restrict__ bq, const float* __restrict__ bk,
    const float* __restrict__ bv, const float* __restrict__ bo,
    ushort* __restrict__ wqkvT, ushort* __restrict__ woT, float* __restrict__ bcat) {
  const int n = blockIdx.x * 256 + threadIdx.x;
  const int k8 = blockIdx.y;
  const float* src; int ld; ushort* dst;
  if (n < 576)      { src = Wq + n;        ld = C_;  dst = wqkvT + (size_t)n * C_; }
  else if (n < 768) { src = Wk + (n - 576); ld = KVC_; dst = wqkvT + (size_t)n * C_; }
  else if (n < 960) { src = Wv + (n - 768); ld = KVC_; dst = wqkvT + (size_t)n * C_; }
  else              { src = Wo + (n - 960); ld = C_;  dst = woT + (size_t)(n - 960) * C_; }
  union { ushort u[8]; i32x4 v; } t;
  #pragma unroll
  for (int e = 0; e < 8; e++) t.u[e] = f2bf(src[(size_t)(k8 * 8 + e) * ld]);
  *reinterpret_cast<i32x4*>(dst + k8 * 8) = t.v;
  if (k8 == 0) {
    if (n < 576)      bcat[n] = bq[n];
    else if (n < 768) bcat[n] = bk[n - 576];
    else if (n < 960) bcat[n] = bv[n - 768];
    else              bcat[n] = bo[n - 960];
  }
}

// ---------------- bf16 MFMA GEMM: C[M,N] = A[M,K] @ Bt[N,K]^T + bias ----------------
template<bool A_F32, bool OUT_BF16>
__global__ __launch_bounds__(256) void gemm_mfma_kernel(
    const void* __restrict__ Ap, const ushort* __restrict__ Bt,
    const float* __restrict__ bias, void* __restrict__ Cp,
    int M, int K, int N, int q_cols) {
  __shared__ ushort As[128 * 64];
  __shared__ ushort Bs[64 * 64];
  const int bm = blockIdx.y * 128, bn = blockIdx.x * 64;
  const int tid = threadIdx.x;
  const int wave = tid >> 6, lane = tid & 63;
  const int lg = lane >> 4, ll = lane & 15;
  const int wm = (wave >> 1) * 64, wn = (wave & 1) * 32;
  f32x4 acc[4][2] = {};

  for (int k0 = 0; k0 < K; k0 += 64) {
    if (A_F32) {
      const float* A = (const float*)Ap;
      #pragma unroll
      for (int i = 0; i < 4; i++) {
        int c = tid + i * 256;
        int row = c >> 3, colb = (c & 7) * 8;
        *reinterpret_cast<i32x4*>(&As[swz(row, colb)]) =
            packrow(A + (size_t)(bm + row) * K + k0 + colb);
      }
    } else {
      const ushort* A = (const ushort*)Ap;
      #pragma unroll
      for (int i = 0; i < 4; i++) {
        int c = tid + i * 256;
        int row = c >> 3, colb = (c & 7) * 8;
        *reinterpret_cast<i32x4*>(&As[swz(row, colb)]) =
            *reinterpret_cast<const i32x4*>(A + (size_t)(bm + row) * K + k0 + colb);
      }
    }
    #pragma unroll
    for (int i = 0; i < 2; i++) {
      int c = tid + i * 256;
      int row = c >> 3, colb = (c & 7) * 8;
      *reinterpret_cast<i32x4*>(&Bs[swz(row, colb)]) =
          *reinterpret_cast<const i32x4*>(Bt + (size_t)(bn + row) * K + k0 + colb);
    }
    __syncthreads();

    bf16x8 af[4][2], bfr[2][2];
    #pragma unroll
    for (int mt = 0; mt < 4; mt++) {
      af[mt][0] = *reinterpret_cast<const bf16x8*>(&As[swz(wm + mt * 16 + ll, lg * 8)]);
      af[mt][1] = *reinterpret_cast<const bf16x8*>(&As[swz(wm + mt * 16 + ll, 32 + lg * 8)]);
    }
    #pragma unroll
    for (int nt = 0; nt < 2; nt++) {
      bfr[nt][0] = *reinterpret_cast<const bf16x8*>(&Bs[swz(wn + nt * 16 + ll, lg * 8)]);
      bfr[nt][1] = *reinterpret_cast<const bf16x8*>(&Bs[swz(wn + nt * 16 + ll, 32 + lg * 8)]);
    }
    #pragma unroll
    for (int mt = 0; mt < 4; mt++) {
      #pragma unroll
      for (int nt = 0; nt < 2; nt++) {
        acc[mt][nt] = MFMA_16x16x32(af[mt][0], bfr[nt][0], acc[mt][nt]);
        acc[mt][nt] = MFMA_16x16x32(af[mt][1], bfr[nt][1], acc[mt][nt]);
      }
    }
    __syncthreads();
  }

  #pragma unroll
  for (int mt = 0; mt < 4; mt++) {
    #pragma unroll
    for (int nt = 0; nt < 2; nt++) {
      const int col = bn + wn + nt * 16 + ll;
      const float scale = (col < q_cols) ? 0.125f : 1.0f;
      #pragma unroll
      for (int r = 0; r < 4; r++) {
        const int row = bm + wm + mt * 16 + lg * 4 + r;
        const float val = (acc[mt][nt][r] + bias[col]) * scale;
        if (OUT_BF16) ((ushort*)Cp)[(size_t)row * N + col] = f2bf(val);
        else          ((float*)Cp)[(size_t)row * N + col] = val;
      }
    }
  }
}

// ---------------- Causal GQA flash attention, bf16 MFMA, balanced + dbuf ----------------
// grid (NH, B, 8): block processes q-tiles {bz, 15-bz} sequentially -> 17 tile-iters each.
// 256 threads = 4 waves; wave w owns q-rows w*16..w*16+15 of the current q-tile.
__global__ __launch_bounds__(256) void attn_mfma_kernel(
    const ushort* __restrict__ qkv, ushort* __restrict__ y) {
  const int h = blockIdx.x, b = blockIdx.y;
  const int kvh = h / NREP_;
  const int tid = threadIdx.x;
  const int wave = tid >> 6, lane = tid & 63;
  const int lg = lane >> 4, ll = lane & 15;
  const int w16 = wave << 4;

  __shared__ ushort Ks[2][64 * 64];
  __shared__ ushort Vts[2][64 * 64];   // Vts[d][key]
  __shared__ ushort Ps[4][16 * 64];

  // staging geometry (fixed per thread)
  const int kr0 = tid >> 3, kcb = (tid & 7) << 3;        // K chunk 0: rows 0..31
  const int kr1 = (tid + 256) >> 3;                      // K chunk 1: rows 32..63
  const int vkey = tid & 63, db = (tid >> 6) << 4;       // V: 16 d per thread

  i32x4 kreg0, kreg1, vreg0, vreg1;

  #pragma unroll 1
  for (int phase = 0; phase < 2; phase++) {
    const int qt = (phase == 0) ? (int)blockIdx.z : 15 - (int)blockIdx.z;
    const int qrow0 = qt << 6;

    // Q A-fragments straight from global (bf16, pre-scaled by 0.125)
    const ushort* qrow = qkv + (size_t)(b * T_ + qrow0 + w16 + ll) * NQKV_ + h * HD_;
    const bf16x8 qa0 = *reinterpret_cast<const bf16x8*>(qrow + lg * 8);
    const bf16x8 qa1 = *reinterpret_cast<const bf16x8*>(qrow + 32 + lg * 8);

    f32x4 o[4] = {};
    float m_i[4] = {-INFINITY, -INFINITY, -INFINITY, -INFINITY};
    float l_i[4] = {0.f, 0.f, 0.f, 0.f};

    // ---- prologue: stage jt=0 into buf 0
    {
      const size_t rb = (size_t)(b * T_);
      kreg0 = *reinterpret_cast<const i32x4*>(qkv + (rb + kr0) * NQKV_ + 576 + kvh * HD_ + kcb);
      kreg1 = *reinterpret_cast<const i32x4*>(qkv + (rb + kr1) * NQKV_ + 576 + kvh * HD_ + kcb);
      const ushort* vsrc = qkv + (rb + vkey) * NQKV_ + 768 + kvh * HD_ + db;
      vreg0 = *reinterpret_cast<const i32x4*>(vsrc);
      vreg1 = *reinterpret_cast<const i32x4*>(vsrc + 8);
    }
    __syncthreads();  // phase B: prior-phase readers of buf0 done (no-op for phase A)
    {
      *reinterpret_cast<i32x4*>(&Ks[0][swz(kr0, kcb)]) = kreg0;
      *reinterpret_cast<i32x4*>(&Ks[0][swz(kr1, kcb)]) = kreg1;
      union { i32x4 v; ushort u[8]; } t0, t1; t0.v = vreg0; t1.v = vreg1;
      #pragma unroll
      for (int e = 0; e < 8; e++) {
        Vts[0][swz(db + e, vkey)] = t0.u[e];
        Vts[0][swz(db + 8 + e, vkey)] = t1.u[e];
      }
    }
    __syncthreads();

    #pragma unroll 1
    for (int jt = 0; jt <= qt; jt++) {
      const int cur = jt & 1;
      // ---- async prefetch of tile jt+1 into registers
      if (jt < qt) {
        const size_t rb = (size_t)(b * T_ + ((jt + 1) << 6));
        kreg0 = *reinterpret_cast<const i32x4*>(qkv + (rb + kr0) * NQKV_ + 576 + kvh * HD_ + kcb);
        kreg1 = *reinterpret_cast<const i32x4*>(qkv + (rb + kr1) * NQKV_ + 576 + kvh * HD_ + kcb);
        const ushort* vsrc = qkv + (rb + vkey) * NQKV_ + 768 + kvh * HD_ + db;
        vreg0 = *reinterpret_cast<const i32x4*>(vsrc);
        vreg1 = *reinterpret_cast<const i32x4*>(vsrc + 8);
      }

      // ---- S = Q K^T (8 MFMA)
      f32x4 s[4] = {};
      #pragma unroll
      for (int kc = 0; kc < 4; kc++) {
        const bf16x8 kb0 = *reinterpret_cast<const bf16x8*>(&Ks[cur][swz(kc * 16 + ll, lg * 8)]);
        const bf16x8 kb1 = *reinterpret_cast<const bf16x8*>(&Ks[cur][swz(kc * 16 + ll, 32 + lg * 8)]);
        s[kc] = MFMA_16x16x32(qa0, kb0, s[kc]);
        s[kc] = MFMA_16x16x32(qa1, kb1, s[kc]);
      }

      // ---- online softmax; lane holds S[w16+lg*4+r][kc*16+ll] (pre-scaled)
      if (jt == qt) {
        #pragma unroll
        for (int kc = 0; kc < 4; kc++)
          #pragma unroll
          for (int r = 0; r < 4; r++)
            if (kc * 16 + ll > w16 + lg * 4 + r) s[kc][r] = -INFINITY;
      }
      float al[4];
      #pragma unroll
      for (int r = 0; r < 4; r++) {
        float t0 = fmaxf(fmaxf(s[0][r], s[1][r]), fmaxf(s[2][r], s[3][r]));
        t0 = fmaxf(t0, __shfl_xor(t0, 1));
        t0 = fmaxf(t0, __shfl_xor(t0, 2));
        t0 = fmaxf(t0, __shfl_xor(t0, 4));
        t0 = fmaxf(t0, __shfl_xor(t0, 8));
        const float mn = fmaxf(m_i[r], t0);
        al[r] = __expf(m_i[r] - mn);
        m_i[r] = mn;
      }
      ushort* Pw = Ps[wave];
      #pragma unroll
      for (int r = 0; r < 4; r++) {
        float rs = 0.f;
        #pragma unroll
        for (int kc = 0; kc < 4; kc++) {
          const float p = __expf(s[kc][r] - m_i[r]);
          rs += p;
          Pw[swz(lg * 4 + r, kc * 16 + ll)] = f2bf(p);
        }
        rs += __shfl_xor(rs, 1);
        rs += __shfl_xor(rs, 2);
        rs += __shfl_xor(rs, 4);
        rs += __shfl_xor(rs, 8);
        l_i[r] = l_i[r] * al[r] + rs;
        o[0][r] *= al[r]; o[1][r] *= al[r]; o[2][r] *= al[r]; o[3][r] *= al[r];
      }

      // ---- O += P V (8 MFMA)
      #pragma unroll
      for (int kh = 0; kh < 2; kh++) {
        const bf16x8 pa = *reinterpret_cast<const bf16x8*>(&Pw[swz(ll, kh * 32 + lg * 8)]);
        #pragma unroll
        for (int d0 = 0; d0 < 4; d0++) {
          const bf16x8 vb = *reinterpret_cast<const bf16x8*>(&Vts[cur][swz(d0 * 16 + ll, kh * 32 + lg * 8)]);
          o[d0] = MFMA_16x16x32(pa, vb, o[d0]);
        }
      }

      // ---- write prefetched tile into the other buffer
      if (jt < qt) {
        __syncthreads();  // all waves done reading buf[cur^1] (iter jt-1)
        const int nxt = cur ^ 1;
        *reinterpret_cast<i32x4*>(&Ks[nxt][swz(kr0, kcb)]) = kreg0;
        *reinterpret_cast<i32x4*>(&Ks[nxt][swz(kr1, kcb)]) = kreg1;
        union { i32x4 v; ushort u[8]; } t0, t1; t0.v = vreg0; t1.v = vreg1;
        #pragma unroll
        for (int e = 0; e < 8; e++) {
          Vts[nxt][swz(db + e, vkey)] = t0.u[e];
          Vts[nxt][swz(db + 8 + e, vkey)] = t1.u[e];
        }
        __syncthreads();  // writes visible before next iter's reads
      }
    }

    // ---- epilogue: y bf16
    #pragma unroll
    for (int r = 0; r < 4; r++) {
      const float inv = 1.f / l_i[r];
      ushort* yrow = y + (size_t)(b * T_ + qrow0 + w16 + lg * 4 + r) * C_ + h * HD_;
      #pragma unroll
      for (int d0 = 0; d0 < 4; d0++) {
        yrow[d0 * 16 + ll] = f2bf(o[d0][r] * inv);
      }
    }
  }
}

extern "C" void kernel_launch(void* const* d_in, const int* in_sizes, int n_in,
                              void* d_out, int out_size, void* d_ws, size_t ws_size,
                              hipStream_t stream) {
  const float* x  = (const float*)d_in[0];
  const float* Wq = (const float*)d_in[1];
  const float* bq = (const float*)d_in[2];
  const float* Wk = (const float*)d_in[3];
  const float* bk = (const float*)d_in[4];
  const float* Wv = (const float*)d_in[5];
  const float* bv = (const float*)d_in[6];
  const float* Wo = (const float*)d_in[7];
  const float* bo = (const float*)d_in[8];
  float* out = (float*)d_out;

  const int M = B_ * T_;  // 8192
  ushort* wqkvT = (ushort*)d_ws;                      // [960][576]
  ushort* woT   = wqkvT + (size_t)NQKV_ * C_;          // [576][576]
  float*  bcat  = (float*)(woT + (size_t)C_ * C_);     // [1536]
  ushort* qkv   = (ushort*)(bcat + 1536);              // [8192][960]
  ushort* y     = qkv + (size_t)M * NQKV_;             // [8192][576]

  convert_w_kernel<<<dim3(6, 72), 256, 0, stream>>>(Wq, Wk, Wv, Wo, bq, bk, bv, bo,
                                                    wqkvT, woT, bcat);
  gemm_mfma_kernel<true, true><<<dim3(NQKV_ / 64, M / 128), 256, 0, stream>>>(
      x, wqkvT, bcat, qkv, M, C_, NQKV_, 576);
  attn_mfma_kernel<<<dim3(NH_, B_, 8), 256, 0, stream>>>(qkv, y);
  gemm_mfma_kernel<false, false><<<dim3(C_ / 64, M / 128), 256, 0, stream>>>(
      y, woT, bcat + NQKV_, out, M, C_, C_, 0);
}

// Round 5
// 123.211 us; speedup vs baseline: 19.6592x; 1.0313x over previous
//
#include <hip/hip_runtime.h>
#include <hip/hip_bf16.h>
#include <math.h>

#define B_    8
#define T_    1024
#define C_    576
#define NH_   9
#define NKV_  3
#define HD_   64
#define KVC_  192
#define NREP_ 3
#define NQKV_ 960   // 576 + 192 + 192

typedef __attribute__((ext_vector_type(8))) short bf16x8;
typedef __attribute__((ext_vector_type(4))) float f32x4;
typedef __attribute__((ext_vector_type(4))) int i32x4;

#define MFMA_16x16x32(a, b, c) __builtin_amdgcn_mfma_f32_16x16x32_bf16((a), (b), (c), 0, 0, 0)

__device__ __forceinline__ ushort f2bf(float f) {
  __hip_bfloat16 h = __float2bfloat16(f);
  return *reinterpret_cast<const ushort*>(&h);
}

// swizzled ushort-index into a row-stride-64(bf16) LDS tile (XOR bank swizzle)
__device__ __forceinline__ int swz(int row, int col) {
  int byte = (row << 7) + (col << 1);
  return (byte ^ ((row & 7) << 4)) >> 1;
}

// 8 consecutive fp32 -> packed 8x bf16 (16B)
__device__ __forceinline__ i32x4 packrow(const float* src) {
  const float4 a = *reinterpret_cast<const float4*>(src);
  const float4 b = *reinterpret_cast<const float4*>(src + 4);
  union { ushort u[8]; i32x4 v; } t;
  t.u[0] = f2bf(a.x); t.u[1] = f2bf(a.y); t.u[2] = f2bf(a.z); t.u[3] = f2bf(a.w);
  t.u[4] = f2bf(b.x); t.u[5] = f2bf(b.y); t.u[6] = f2bf(b.z); t.u[7] = f2bf(b.w);
  return t.v;
}

// ---------------- weight convert+transpose: Wt[n][k] bf16, bias concat ----------------
__global__ __launch_bounds__(256) void convert_w_kernel(
    const float* __restrict__ Wq, const float* __restrict__ Wk,
    const float* __restrict__ Wv, const float* __restrict__ Wo,
    const float* __restrict__ bq, const float* __restrict__ bk,
    const float* __restrict__ bv, const float* __restrict__ bo,
    ushort* __restrict__ wqkvT, ushort* __restrict__ woT, float* __restrict__ bcat) {
  const int n = blockIdx.x * 256 + threadIdx.x;
  const int k8 = blockIdx.y;
  const float* src; int ld; ushort* dst;
  if (n < 576)      { src = Wq + n;        ld = C_;  dst = wqkvT + (size_t)n * C_; }
  else if (n < 768) { src = Wk + (n - 576); ld = KVC_; dst = wqkvT + (size_t)n * C_; }
  else if (n < 960) { src = Wv + (n - 768); ld = KVC_; dst = wqkvT + (size_t)n * C_; }
  else              { src = Wo + (n - 960); ld = C_;  dst = woT + (size_t)(n - 960) * C_; }
  union { ushort u[8]; i32x4 v; } t;
  #pragma unroll
  for (int e = 0; e < 8; e++) t.u[e] = f2bf(src[(size_t)(k8 * 8 + e) * ld]);
  *reinterpret_cast<i32x4*>(dst + k8 * 8) = t.v;
  if (k8 == 0) {
    if (n < 576)      bcat[n] = bq[n];
    else if (n < 768) bcat[n] = bk[n - 576];
    else if (n < 960) bcat[n] = bv[n - 768];
    else              bcat[n] = bo[n - 960];
  }
}

// ---------------- bf16 MFMA GEMM: C[M,N] = A[M,K] @ Bt[N,K]^T + bias ----------------
// 256x64 tile, 4 waves stacked in M; per wave 64x64 out = 4x4 16x16 frags, BK=64.
template<bool A_F32, bool OUT_BF16>
__global__ __launch_bounds__(256, 2) void gemm_mfma_kernel(
    const void* __restrict__ Ap, const ushort* __restrict__ Bt,
    const float* __restrict__ bias, void* __restrict__ Cp,
    int M, int K, int N, int q_cols) {
  __shared__ ushort As[256 * 64];
  __shared__ ushort Bs[64 * 64];
  const int bm = blockIdx.y * 256, bn = blockIdx.x * 64;
  const int tid = threadIdx.x;
  const int wave = tid >> 6, lane = tid & 63;
  const int lg = lane >> 4, ll = lane & 15;
  const int wm = wave * 64;
  f32x4 acc[4][4] = {};

  for (int k0 = 0; k0 < K; k0 += 64) {
    // stage A tile (256 x 64 bf16): 2048 16B-chunks, 8 per thread
    if (A_F32) {
      const float* A = (const float*)Ap;
      #pragma unroll
      for (int i = 0; i < 8; i++) {
        int c = tid + i * 256;
        int row = c >> 3, colb = (c & 7) * 8;
        *reinterpret_cast<i32x4*>(&As[swz(row, colb)]) =
            packrow(A + (size_t)(bm + row) * K + k0 + colb);
      }
    } else {
      const ushort* A = (const ushort*)Ap;
      #pragma unroll
      for (int i = 0; i < 8; i++) {
        int c = tid + i * 256;
        int row = c >> 3, colb = (c & 7) * 8;
        *reinterpret_cast<i32x4*>(&As[swz(row, colb)]) =
            *reinterpret_cast<const i32x4*>(A + (size_t)(bm + row) * K + k0 + colb);
      }
    }
    // stage Bt tile (64 x 64): 512 chunks, 2 per thread
    #pragma unroll
    for (int i = 0; i < 2; i++) {
      int c = tid + i * 256;
      int row = c >> 3, colb = (c & 7) * 8;
      *reinterpret_cast<i32x4*>(&Bs[swz(row, colb)]) =
          *reinterpret_cast<const i32x4*>(Bt + (size_t)(bn + row) * K + k0 + colb);
    }
    __syncthreads();

    bf16x8 af[4][2], bfr[4][2];
    #pragma unroll
    for (int mt = 0; mt < 4; mt++) {
      af[mt][0] = *reinterpret_cast<const bf16x8*>(&As[swz(wm + mt * 16 + ll, lg * 8)]);
      af[mt][1] = *reinterpret_cast<const bf16x8*>(&As[swz(wm + mt * 16 + ll, 32 + lg * 8)]);
    }
    #pragma unroll
    for (int nt = 0; nt < 4; nt++) {
      bfr[nt][0] = *reinterpret_cast<const bf16x8*>(&Bs[swz(nt * 16 + ll, lg * 8)]);
      bfr[nt][1] = *reinterpret_cast<const bf16x8*>(&Bs[swz(nt * 16 + ll, 32 + lg * 8)]);
    }
    #pragma unroll
    for (int mt = 0; mt < 4; mt++) {
      #pragma unroll
      for (int nt = 0; nt < 4; nt++) {
        acc[mt][nt] = MFMA_16x16x32(af[mt][0], bfr[nt][0], acc[mt][nt]);
        acc[mt][nt] = MFMA_16x16x32(af[mt][1], bfr[nt][1], acc[mt][nt]);
      }
    }
    __syncthreads();
  }

  #pragma unroll
  for (int mt = 0; mt < 4; mt++) {
    #pragma unroll
    for (int nt = 0; nt < 4; nt++) {
      const int col = bn + nt * 16 + ll;
      const float scale = (col < q_cols) ? 0.125f : 1.0f;
      #pragma unroll
      for (int r = 0; r < 4; r++) {
        const int row = bm + wm + mt * 16 + lg * 4 + r;
        const float val = (acc[mt][nt][r] + bias[col]) * scale;
        if (OUT_BF16) ((ushort*)Cp)[(size_t)row * N + col] = f2bf(val);
        else          ((float*)Cp)[(size_t)row * N + col] = val;
      }
    }
  }
}

// ---------------- Causal GQA flash attention, swapped-QK bf16 MFMA ----------------
// grid (16, NH, B): qt = 15 - bx (longest blocks dispatch first), one 64-row q-tile/block.
// 256 threads = 4 waves; wave w owns q-rows w*16..w*16+15. Single-buffered K/V + reg prefetch.
__global__ __launch_bounds__(256) void attn_mfma_kernel(
    const ushort* __restrict__ qkv, ushort* __restrict__ y) {
  const int qt = 15 - blockIdx.x, h = blockIdx.y, b = blockIdx.z;
  const int kvh = h / NREP_;
  const int tid = threadIdx.x;
  const int wave = tid >> 6, lane = tid & 63;
  const int lg = lane >> 4, ll = lane & 15;
  const int w16 = wave << 4;
  const int qrow0 = qt << 6;

  __shared__ ushort Ks[64 * 64];
  __shared__ ushort Vts[64 * 64];   // Vts[d][key]
  __shared__ ushort Ps[4][16 * 64]; // per-wave P staging, rows = q-local

  // staging geometry
  const int kr0 = tid >> 3, kcb = (tid & 7) << 3;   // K chunk 0: rows 0..31
  const int kr1 = kr0 + 32;                          // K chunk 1: rows 32..63
  const int vkey = tid & 63, db = (tid >> 6) << 4;   // V: 16 d per thread

  // Q B-fragments straight from global (bf16, pre-scaled by 0.125)
  const ushort* qrow = qkv + (size_t)(b * T_ + qrow0 + w16 + ll) * NQKV_ + h * HD_;
  const bf16x8 qa0 = *reinterpret_cast<const bf16x8*>(qrow + lg * 8);
  const bf16x8 qa1 = *reinterpret_cast<const bf16x8*>(qrow + 32 + lg * 8);

  f32x4 o[4] = {};   // o[d0][r] = O[w16 + lg*4 + r][d0*16 + ll]
  float m_i = -INFINITY, l_i = 0.f;   // per-lane: q-row = w16 + ll

  i32x4 kreg0, kreg1, vreg0, vreg1;
  // prologue: load tile 0
  {
    const size_t rb = (size_t)(b * T_);
    kreg0 = *reinterpret_cast<const i32x4*>(qkv + (rb + kr0) * NQKV_ + 576 + kvh * HD_ + kcb);
    kreg1 = *reinterpret_cast<const i32x4*>(qkv + (rb + kr1) * NQKV_ + 576 + kvh * HD_ + kcb);
    const ushort* vsrc = qkv + (rb + vkey) * NQKV_ + 768 + kvh * HD_ + db;
    vreg0 = *reinterpret_cast<const i32x4*>(vsrc);
    vreg1 = *reinterpret_cast<const i32x4*>(vsrc + 8);
    *reinterpret_cast<i32x4*>(&Ks[swz(kr0, kcb)]) = kreg0;
    *reinterpret_cast<i32x4*>(&Ks[swz(kr1, kcb)]) = kreg1;
    union { i32x4 v; ushort u[8]; } t0, t1; t0.v = vreg0; t1.v = vreg1;
    #pragma unroll
    for (int e = 0; e < 8; e++) {
      Vts[swz(db + e, vkey)] = t0.u[e];
      Vts[swz(db + 8 + e, vkey)] = t1.u[e];
    }
  }
  __syncthreads();

  #pragma unroll 1
  for (int jt = 0; jt <= qt; jt++) {
    // prefetch next tile into registers (hides under compute)
    if (jt < qt) {
      const size_t rb = (size_t)(b * T_ + ((jt + 1) << 6));
      kreg0 = *reinterpret_cast<const i32x4*>(qkv + (rb + kr0) * NQKV_ + 576 + kvh * HD_ + kcb);
      kreg1 = *reinterpret_cast<const i32x4*>(qkv + (rb + kr1) * NQKV_ + 576 + kvh * HD_ + kcb);
      const ushort* vsrc = qkv + (rb + vkey) * NQKV_ + 768 + kvh * HD_ + db;
      vreg0 = *reinterpret_cast<const i32x4*>(vsrc);
      vreg1 = *reinterpret_cast<const i32x4*>(vsrc + 8);
    }

    // ---- S^T = K Q^T (swapped operands): lane holds S[key=kc*16+lg*4+r][q=w16+ll]
    f32x4 s[4] = {};
    #pragma unroll
    for (int kc = 0; kc < 4; kc++) {
      const bf16x8 kb0 = *reinterpret_cast<const bf16x8*>(&Ks[swz(kc * 16 + ll, lg * 8)]);
      const bf16x8 kb1 = *reinterpret_cast<const bf16x8*>(&Ks[swz(kc * 16 + ll, 32 + lg * 8)]);
      s[kc] = MFMA_16x16x32(kb0, qa0, s[kc]);
      s[kc] = MFMA_16x16x32(kb1, qa1, s[kc]);
    }

    // ---- causal mask on diagonal tile: key_local > q_local
    if (jt == qt) {
      #pragma unroll
      for (int kc = 0; kc < 4; kc++)
        #pragma unroll
        for (int r = 0; r < 4; r++)
          if (kc * 16 + lg * 4 + r > w16 + ll) s[kc][r] = -INFINITY;
    }

    // ---- in-register online softmax for own q-row (w16+ll)
    float t0 = s[0][0];
    #pragma unroll
    for (int kc = 0; kc < 4; kc++)
      #pragma unroll
      for (int r = 0; r < 4; r++) t0 = fmaxf(t0, s[kc][r]);
    t0 = fmaxf(t0, __shfl_xor(t0, 16));
    t0 = fmaxf(t0, __shfl_xor(t0, 32));
    const float mn = fmaxf(m_i, t0);
    const float al = __expf(m_i - mn);
    m_i = mn;

    ushort* Pw = Ps[wave];
    float rs = 0.f;
    #pragma unroll
    for (int kc = 0; kc < 4; kc++) {
      float p0 = __expf(s[kc][0] - mn);
      float p1 = __expf(s[kc][1] - mn);
      float p2 = __expf(s[kc][2] - mn);
      float p3 = __expf(s[kc][3] - mn);
      rs += (p0 + p1) + (p2 + p3);
      uint w01 = (uint)f2bf(p0) | ((uint)f2bf(p1) << 16);
      uint w23 = (uint)f2bf(p2) | ((uint)f2bf(p3) << 16);
      *reinterpret_cast<uint*>(&Pw[swz(ll, kc * 16 + lg * 4)])     = w01;
      *reinterpret_cast<uint*>(&Pw[swz(ll, kc * 16 + lg * 4 + 2)]) = w23;
    }
    rs += __shfl_xor(rs, 16);
    rs += __shfl_xor(rs, 32);
    l_i = l_i * al + rs;

    // ---- rescale O (alpha broadcast from lane holding that q-row)
    #pragma unroll
    for (int r = 0; r < 4; r++) {
      const float ar = __shfl(al, lg * 4 + r);
      o[0][r] *= ar; o[1][r] *= ar; o[2][r] *= ar; o[3][r] *= ar;
    }

    // ---- O += P V (8 MFMA; P per-wave in LDS, no barrier needed)
    #pragma unroll
    for (int kh = 0; kh < 2; kh++) {
      const bf16x8 pa = *reinterpret_cast<const bf16x8*>(&Pw[swz(ll, kh * 32 + lg * 8)]);
      #pragma unroll
      for (int d0 = 0; d0 < 4; d0++) {
        const bf16x8 vb = *reinterpret_cast<const bf16x8*>(&Vts[swz(d0 * 16 + ll, kh * 32 + lg * 8)]);
        o[d0] = MFMA_16x16x32(pa, vb, o[d0]);
      }
    }

    // ---- write prefetched tile (single buffer: all readers must be done)
    if (jt < qt) {
      __syncthreads();
      *reinterpret_cast<i32x4*>(&Ks[swz(kr0, kcb)]) = kreg0;
      *reinterpret_cast<i32x4*>(&Ks[swz(kr1, kcb)]) = kreg1;
      union { i32x4 v; ushort u[8]; } t0u, t1u; t0u.v = vreg0; t1u.v = vreg1;
      #pragma unroll
      for (int e = 0; e < 8; e++) {
        Vts[swz(db + e, vkey)] = t0u.u[e];
        Vts[swz(db + 8 + e, vkey)] = t1u.u[e];
      }
      __syncthreads();
    }
  }

  // ---- epilogue: y bf16 (l broadcast per output row)
  #pragma unroll
  for (int r = 0; r < 4; r++) {
    const float lr = __shfl(l_i, lg * 4 + r);
    const float inv = 1.f / lr;
    ushort* yrow = y + (size_t)(b * T_ + qrow0 + w16 + lg * 4 + r) * C_ + h * HD_;
    #pragma unroll
    for (int d0 = 0; d0 < 4; d0++) {
      yrow[d0 * 16 + ll] = f2bf(o[d0][r] * inv);
    }
  }
}

extern "C" void kernel_launch(void* const* d_in, const int* in_sizes, int n_in,
                              void* d_out, int out_size, void* d_ws, size_t ws_size,
                              hipStream_t stream) {
  const float* x  = (const float*)d_in[0];
  const float* Wq = (const float*)d_in[1];
  const float* bq = (const float*)d_in[2];
  const float* Wk = (const float*)d_in[3];
  const float* bk = (const float*)d_in[4];
  const float* Wv = (const float*)d_in[5];
  const float* bv = (const float*)d_in[6];
  const float* Wo = (const float*)d_in[7];
  const float* bo = (const float*)d_in[8];
  float* out = (float*)d_out;

  const int M = B_ * T_;  // 8192
  ushort* wqkvT = (ushort*)d_ws;                      // [960][576]
  ushort* woT   = wqkvT + (size_t)NQKV_ * C_;          // [576][576]
  float*  bcat  = (float*)(woT + (size_t)C_ * C_);     // [1536]
  ushort* qkv   = (ushort*)(bcat + 1536);              // [8192][960]
  ushort* y     = qkv + (size_t)M * NQKV_;             // [8192][576]

  convert_w_kernel<<<dim3(6, 72), 256, 0, stream>>>(Wq, Wk, Wv, Wo, bq, bk, bv, bo,
                                                    wqkvT, woT, bcat);
  gemm_mfma_kernel<true, true><<<dim3(NQKV_ / 64, M / 256), 256, 0, stream>>>(
      x, wqkvT, bcat, qkv, M, C_, NQKV_, 576);
  attn_mfma_kernel<<<dim3(16, NH_, B_), 256, 0, stream>>>(qkv, y);
  gemm_mfma_kernel<false, false><<<dim3(C_ / 64, M / 256), 256, 0, stream>>>(
      y, woT, bcat + NQKV_, out, M, C_, C_, 0);
}

// Round 7
// 92.823 us; speedup vs baseline: 26.0950x; 1.3274x over previous
//
#include <hip/hip_runtime.h>
#include <hip/hip_bf16.h>
#include <math.h>

#define B_    8
#define T_    1024
#define C_    576
#define NH_   9
#define NKV_  3
#define HD_   64
#define KVC_  192
#define NREP_ 3
#define NQKV_ 960   // 576 + 192 + 192

typedef __attribute__((ext_vector_type(8))) short bf16x8;
typedef __attribute__((ext_vector_type(4))) float f32x4;
typedef __attribute__((ext_vector_type(4))) int i32x4;

#define MFMA_16x16x32(a, b, c) __builtin_amdgcn_mfma_f32_16x16x32_bf16((a), (b), (c), 0, 0, 0)

__device__ __forceinline__ ushort f2bf(float f) {
  __hip_bfloat16 h = __float2bfloat16(f);
  return *reinterpret_cast<const ushort*>(&h);
}

// swizzled ushort-index into a row-stride-64(bf16) LDS tile (XOR bank swizzle)
__device__ __forceinline__ int swz(int row, int col) {
  int byte = (row << 7) + (col << 1);
  return (byte ^ ((row & 7) << 4)) >> 1;
}

// 8 consecutive fp32 -> packed 8x bf16 (16B)
__device__ __forceinline__ i32x4 packrow(const float* src) {
  const float4 a = *reinterpret_cast<const float4*>(src);
  const float4 b = *reinterpret_cast<const float4*>(src + 4);
  union { ushort u[8]; i32x4 v; } t;
  t.u[0] = f2bf(a.x); t.u[1] = f2bf(a.y); t.u[2] = f2bf(a.z); t.u[3] = f2bf(a.w);
  t.u[4] = f2bf(b.x); t.u[5] = f2bf(b.y); t.u[6] = f2bf(b.z); t.u[7] = f2bf(b.w);
  return t.v;
}

// ---------------- weight convert+transpose: Wt[n][k] bf16, bias concat ----------------
__global__ __launch_bounds__(256) void convert_w_kernel(
    const float* __restrict__ Wq, const float* __restrict__ Wk,
    const float* __restrict__ Wv, const float* __restrict__ Wo,
    const float* __restrict__ bq, const float* __restrict__ bk,
    const float* __restrict__ bv, const float* __restrict__ bo,
    ushort* __restrict__ wqkvT, ushort* __restrict__ woT, float* __restrict__ bcat) {
  const int n = blockIdx.x * 256 + threadIdx.x;
  const int k8 = blockIdx.y;
  const float* src; int ld; ushort* dst;
  if (n < 576)      { src = Wq + n;        ld = C_;  dst = wqkvT + (size_t)n * C_; }
  else if (n < 768) { src = Wk + (n - 576); ld = KVC_; dst = wqkvT + (size_t)n * C_; }
  else if (n < 960) { src = Wv + (n - 768); ld = KVC_; dst = wqkvT + (size_t)n * C_; }
  else              { src = Wo + (n - 960); ld = C_;  dst = woT + (size_t)(n - 960) * C_; }
  union { ushort u[8]; i32x4 v; } t;
  #pragma unroll
  for (int e = 0; e < 8; e++) t.u[e] = f2bf(src[(size_t)(k8 * 8 + e) * ld]);
  *reinterpret_cast<i32x4*>(dst + k8 * 8) = t.v;
  if (k8 == 0) {
    if (n < 576)      bcat[n] = bq[n];
    else if (n < 768) bcat[n] = bk[n - 576];
    else if (n < 960) bcat[n] = bv[n - 768];
    else              bcat[n] = bo[n - 960];
  }
}

// ---------------- bf16 MFMA GEMM: C[M,N] = A[M,K] @ Bt[N,K]^T + bias ----------------
// 128x64 tile, 4 waves (2x2), each wave 64x32 = 4x2 16x16 frags, BK=64. (round-3 proven)
template<bool A_F32, bool OUT_BF16>
__global__ __launch_bounds__(256) void gemm_mfma_kernel(
    const void* __restrict__ Ap, const ushort* __restrict__ Bt,
    const float* __restrict__ bias, void* __restrict__ Cp,
    int M, int K, int N, int q_cols) {
  __shared__ ushort As[128 * 64];
  __shared__ ushort Bs[64 * 64];
  const int bm = blockIdx.y * 128, bn = blockIdx.x * 64;
  const int tid = threadIdx.x;
  const int wave = tid >> 6, lane = tid & 63;
  const int lg = lane >> 4, ll = lane & 15;
  const int wm = (wave >> 1) * 64, wn = (wave & 1) * 32;
  f32x4 acc[4][2] = {};

  for (int k0 = 0; k0 < K; k0 += 64) {
    if (A_F32) {
      const float* A = (const float*)Ap;
      #pragma unroll
      for (int i = 0; i < 4; i++) {
        int c = tid + i * 256;
        int row = c >> 3, colb = (c & 7) * 8;
        *reinterpret_cast<i32x4*>(&As[swz(row, colb)]) =
            packrow(A + (size_t)(bm + row) * K + k0 + colb);
      }
    } else {
      const ushort* A = (const ushort*)Ap;
      #pragma unroll
      for (int i = 0; i < 4; i++) {
        int c = tid + i * 256;
        int row = c >> 3, colb = (c & 7) * 8;
        *reinterpret_cast<i32x4*>(&As[swz(row, colb)]) =
            *reinterpret_cast<const i32x4*>(A + (size_t)(bm + row) * K + k0 + colb);
      }
    }
    #pragma unroll
    for (int i = 0; i < 2; i++) {
      int c = tid + i * 256;
      int row = c >> 3, colb = (c & 7) * 8;
      *reinterpret_cast<i32x4*>(&Bs[swz(row, colb)]) =
          *reinterpret_cast<const i32x4*>(Bt + (size_t)(bn + row) * K + k0 + colb);
    }
    __syncthreads();

    bf16x8 af[4][2], bfr[2][2];
    #pragma unroll
    for (int mt = 0; mt < 4; mt++) {
      af[mt][0] = *reinterpret_cast<const bf16x8*>(&As[swz(wm + mt * 16 + ll, lg * 8)]);
      af[mt][1] = *reinterpret_cast<const bf16x8*>(&As[swz(wm + mt * 16 + ll, 32 + lg * 8)]);
    }
    #pragma unroll
    for (int nt = 0; nt < 2; nt++) {
      bfr[nt][0] = *reinterpret_cast<const bf16x8*>(&Bs[swz(wn + nt * 16 + ll, lg * 8)]);
      bfr[nt][1] = *reinterpret_cast<const bf16x8*>(&Bs[swz(wn + nt * 16 + ll, 32 + lg * 8)]);
    }
    #pragma unroll
    for (int mt = 0; mt < 4; mt++) {
      #pragma unroll
      for (int nt = 0; nt < 2; nt++) {
        acc[mt][nt] = MFMA_16x16x32(af[mt][0], bfr[nt][0], acc[mt][nt]);
        acc[mt][nt] = MFMA_16x16x32(af[mt][1], bfr[nt][1], acc[mt][nt]);
      }
    }
    __syncthreads();
  }

  #pragma unroll
  for (int mt = 0; mt < 4; mt++) {
    #pragma unroll
    for (int nt = 0; nt < 2; nt++) {
      const int col = bn + wn + nt * 16 + ll;
      const float scale = (col < q_cols) ? 0.125f : 1.0f;
      #pragma unroll
      for (int r = 0; r < 4; r++) {
        const int row = bm + wm + mt * 16 + lg * 4 + r;
        const float val = (acc[mt][nt][r] + bias[col]) * scale;
        if (OUT_BF16) ((ushort*)Cp)[(size_t)row * N + col] = f2bf(val);
        else          ((float*)Cp)[(size_t)row * N + col] = val;
      }
    }
  }
}

// ---------------- Causal GQA flash attention, swapped-QK bf16 MFMA, KVBLK=128 ----------------
// grid (NH, B, 16): qt = 15 - bz (all longest blocks dispatch first, backfill balances).
// 256 threads = 4 waves; wave w owns q-rows w*16..w*16+15 (lane's q-row = w16 + ll).
// K/V staged as 2x 64x64 swizzled tiles; single buffer + reg prefetch.
__global__ __launch_bounds__(256) void attn_mfma_kernel(
    const ushort* __restrict__ qkv, ushort* __restrict__ y) {
  const int qt = 15 - blockIdx.z, h = blockIdx.x, b = blockIdx.y;
  const int kvh = h / NREP_;
  const int tid = threadIdx.x;
  const int wave = tid >> 6, lane = tid & 63;
  const int lg = lane >> 4, ll = lane & 15;
  const int w16 = wave << 4;
  const int qrow0 = qt << 6;
  const int nk = (qt + 2) >> 1;   // ceil((qt+1)*64 / 128)

  __shared__ ushort Ks[2][64 * 64];    // [sub][key64][d]
  __shared__ ushort Vts[2][64 * 64];   // [sub][d][key64]
  __shared__ ushort Ps[4][2][16 * 64]; // [wave][sub][q16][key64]

  // staging geometry (128 keys per tile; 128 threads per 64-key sub-tile)
  const int ksub = tid >> 7, ktt = tid & 127;
  const int kr = ktt >> 2, kcb = (ktt & 3) << 4;   // K: rows kr, kr+32; d kcb..kcb+15
  const int vkp = ktt & 31, vds = (ktt >> 5) << 4; // V: keys 2vkp,2vkp+1; d vds..vds+15

  // Q B-fragments straight from global (bf16, pre-scaled by 0.125)
  const ushort* qrow = qkv + (size_t)(b * T_ + qrow0 + w16 + ll) * NQKV_ + h * HD_;
  const bf16x8 qa0 = *reinterpret_cast<const bf16x8*>(qrow + lg * 8);
  const bf16x8 qa1 = *reinterpret_cast<const bf16x8*>(qrow + 32 + lg * 8);

  f32x4 o[4] = {};   // o[d0][r] = O[w16 + lg*4 + r][d0*16 + ll]
  float m_i = -INFINITY, l_i = 0.f;   // per-lane: q-row = w16 + ll

  i32x4 kra, krb, krc, krd, va0, va1, vb0, vb1;
  // ---- load tile 0 into regs
  {
    const size_t rb = (size_t)(b * T_);
    const ushort* ks0 = qkv + (rb + ksub * 64 + kr) * NQKV_ + 576 + kvh * HD_ + kcb;
    const ushort* ks1 = ks0 + (size_t)32 * NQKV_;
    kra = *reinterpret_cast<const i32x4*>(ks0);
    krb = *reinterpret_cast<const i32x4*>(ks0 + 8);
    krc = *reinterpret_cast<const i32x4*>(ks1);
    krd = *reinterpret_cast<const i32x4*>(ks1 + 8);
    const ushort* v0 = qkv + (rb + ksub * 64 + vkp * 2) * NQKV_ + 768 + kvh * HD_ + vds;
    const ushort* v1 = v0 + NQKV_;
    va0 = *reinterpret_cast<const i32x4*>(v0); va1 = *reinterpret_cast<const i32x4*>(v0 + 8);
    vb0 = *reinterpret_cast<const i32x4*>(v1); vb1 = *reinterpret_cast<const i32x4*>(v1 + 8);
  }
  // ---- write tile 0
  {
    *reinterpret_cast<i32x4*>(&Ks[ksub][swz(kr, kcb)]) = kra;
    *reinterpret_cast<i32x4*>(&Ks[ksub][swz(kr, kcb + 8)]) = krb;
    *reinterpret_cast<i32x4*>(&Ks[ksub][swz(kr + 32, kcb)]) = krc;
    *reinterpret_cast<i32x4*>(&Ks[ksub][swz(kr + 32, kcb + 8)]) = krd;
    union { i32x4 v; ushort u[8]; } a0, a1, c0, c1;
    a0.v = va0; a1.v = va1; c0.v = vb0; c1.v = vb1;
    #pragma unroll
    for (int e = 0; e < 8; e++) {
      *reinterpret_cast<uint*>(&Vts[ksub][swz(vds + e, vkp * 2)]) =
          (uint)a0.u[e] | ((uint)c0.u[e] << 16);
      *reinterpret_cast<uint*>(&Vts[ksub][swz(vds + 8 + e, vkp * 2)]) =
          (uint)a1.u[e] | ((uint)c1.u[e] << 16);
    }
  }
  __syncthreads();

  #pragma unroll 1
  for (int kt = 0; kt < nk; kt++) {
    // ---- prefetch next 128-key tile into registers (hides under compute)
    if (kt + 1 < nk) {
      const size_t rb = (size_t)(b * T_ + ((kt + 1) << 7));
      const ushort* ks0 = qkv + (rb + ksub * 64 + kr) * NQKV_ + 576 + kvh * HD_ + kcb;
      const ushort* ks1 = ks0 + (size_t)32 * NQKV_;
      kra = *reinterpret_cast<const i32x4*>(ks0);
      krb = *reinterpret_cast<const i32x4*>(ks0 + 8);
      krc = *reinterpret_cast<const i32x4*>(ks1);
      krd = *reinterpret_cast<const i32x4*>(ks1 + 8);
      const ushort* v0 = qkv + (rb + ksub * 64 + vkp * 2) * NQKV_ + 768 + kvh * HD_ + vds;
      const ushort* v1 = v0 + NQKV_;
      va0 = *reinterpret_cast<const i32x4*>(v0); va1 = *reinterpret_cast<const i32x4*>(v0 + 8);
      vb0 = *reinterpret_cast<const i32x4*>(v1); vb1 = *reinterpret_cast<const i32x4*>(v1 + 8);
    }

    // ---- S^T = K Q^T (16 MFMA): lane holds S[key=kc*16+lg*4+r][q=w16+ll]
    f32x4 s[8];
    #pragma unroll
    for (int kc = 0; kc < 8; kc++) {
      const int sub = kc >> 2, kcl = kc & 3;
      const bf16x8 kb0 = *reinterpret_cast<const bf16x8*>(&Ks[sub][swz(kcl * 16 + ll, lg * 8)]);
      const bf16x8 kb1 = *reinterpret_cast<const bf16x8*>(&Ks[sub][swz(kcl * 16 + ll, 32 + lg * 8)]);
      f32x4 z = {};
      z = MFMA_16x16x32(kb0, qa0, z);
      s[kc] = MFMA_16x16x32(kb1, qa1, z);
    }

    // ---- causal mask (last tile only): global key > global q
    if (kt == nk - 1) {
      const int qg = qrow0 + w16 + ll - (kt << 7);
      #pragma unroll
      for (int kc = 0; kc < 8; kc++)
        #pragma unroll
        for (int r = 0; r < 4; r++)
          if (kc * 16 + lg * 4 + r > qg) s[kc][r] = -INFINITY;
    }

    // ---- in-register online softmax for own q-row (w16+ll), defer-max (THR=8)
    float t0 = s[0][0];
    #pragma unroll
    for (int kc = 0; kc < 8; kc++)
      #pragma unroll
      for (int r = 0; r < 4; r++) t0 = fmaxf(t0, s[kc][r]);
    t0 = fmaxf(t0, __shfl_xor(t0, 16));
    t0 = fmaxf(t0, __shfl_xor(t0, 32));
    if (!__all(t0 <= m_i + 8.f)) {
      const float mn = fmaxf(m_i, t0);
      const float al = __expf(m_i - mn);
      m_i = mn;
      l_i *= al;
      #pragma unroll
      for (int r = 0; r < 4; r++) {
        const float ar = __shfl(al, lg * 4 + r);
        o[0][r] *= ar; o[1][r] *= ar; o[2][r] *= ar; o[3][r] *= ar;
      }
    }

    float rs = 0.f;
    #pragma unroll
    for (int kc = 0; kc < 8; kc++) {
      const int sub = kc >> 2, kcl = kc & 3;
      float p0 = __expf(s[kc][0] - m_i);
      float p1 = __expf(s[kc][1] - m_i);
      float p2 = __expf(s[kc][2] - m_i);
      float p3 = __expf(s[kc][3] - m_i);
      rs += (p0 + p1) + (p2 + p3);
      uint w01 = (uint)f2bf(p0) | ((uint)f2bf(p1) << 16);
      uint w23 = (uint)f2bf(p2) | ((uint)f2bf(p3) << 16);
      ushort* Pw = Ps[wave][sub];
      *reinterpret_cast<uint*>(&Pw[swz(ll, kcl * 16 + lg * 4)])     = w01;
      *reinterpret_cast<uint*>(&Pw[swz(ll, kcl * 16 + lg * 4 + 2)]) = w23;
    }
    rs += __shfl_xor(rs, 16);
    rs += __shfl_xor(rs, 32);
    l_i += rs;

    // ---- O += P V (16 MFMA; P per-wave in LDS, no barrier needed)
    #pragma unroll
    for (int kh = 0; kh < 4; kh++) {
      const int sub = kh >> 1, khl = kh & 1;
      const bf16x8 pa = *reinterpret_cast<const bf16x8*>(&Ps[wave][sub][swz(ll, khl * 32 + lg * 8)]);
      #pragma unroll
      for (int d0 = 0; d0 < 4; d0++) {
        const bf16x8 vb = *reinterpret_cast<const bf16x8*>(&Vts[sub][swz(d0 * 16 + ll, khl * 32 + lg * 8)]);
        o[d0] = MFMA_16x16x32(pa, vb, o[d0]);
      }
    }

    // ---- write prefetched tile (single buffer)
    if (kt + 1 < nk) {
      __syncthreads();
      *reinterpret_cast<i32x4*>(&Ks[ksub][swz(kr, kcb)]) = kra;
      *reinterpret_cast<i32x4*>(&Ks[ksub][swz(kr, kcb + 8)]) = krb;
      *reinterpret_cast<i32x4*>(&Ks[ksub][swz(kr + 32, kcb)]) = krc;
      *reinterpret_cast<i32x4*>(&Ks[ksub][swz(kr + 32, kcb + 8)]) = krd;
      union { i32x4 v; ushort u[8]; } a0, a1, c0, c1;
      a0.v = va0; a1.v = va1; c0.v = vb0; c1.v = vb1;
      #pragma unroll
      for (int e = 0; e < 8; e++) {
        *reinterpret_cast<uint*>(&Vts[ksub][swz(vds + e, vkp * 2)]) =
            (uint)a0.u[e] | ((uint)c0.u[e] << 16);
        *reinterpret_cast<uint*>(&Vts[ksub][swz(vds + 8 + e, vkp * 2)]) =
            (uint)a1.u[e] | ((uint)c1.u[e] << 16);
      }
      __syncthreads();
    }
  }

  // ---- epilogue: y bf16 (l broadcast per output row)
  #pragma unroll
  for (int r = 0; r < 4; r++) {
    const float lr = __shfl(l_i, lg * 4 + r);
    const float inv = 1.f / lr;
    ushort* yrow = y + (size_t)(b * T_ + qrow0 + w16 + lg * 4 + r) * C_ + h * HD_;
    #pragma unroll
    for (int d0 = 0; d0 < 4; d0++) {
      yrow[d0 * 16 + ll] = f2bf(o[d0][r] * inv);
    }
  }
}

extern "C" void kernel_launch(void* const* d_in, const int* in_sizes, int n_in,
                              void* d_out, int out_size, void* d_ws, size_t ws_size,
                              hipStream_t stream) {
  const float* x  = (const float*)d_in[0];
  const float* Wq = (const float*)d_in[1];
  const float* bq = (const float*)d_in[2];
  const float* Wk = (const float*)d_in[3];
  const float* bk = (const float*)d_in[4];
  const float* Wv = (const float*)d_in[5];
  const float* bv = (const float*)d_in[6];
  const float* Wo = (const float*)d_in[7];
  const float* bo = (const float*)d_in[8];
  float* out = (float*)d_out;

  const int M = B_ * T_;  // 8192
  ushort* wqkvT = (ushort*)d_ws;                      // [960][576]
  ushort* woT   = wqkvT + (size_t)NQKV_ * C_;          // [576][576]
  float*  bcat  = (float*)(woT + (size_t)C_ * C_);     // [1536]
  ushort* qkv   = (ushort*)(bcat + 1536);              // [8192][960]
  ushort* y     = qkv + (size_t)M * NQKV_;             // [8192][576]

  convert_w_kernel<<<dim3(6, 72), 256, 0, stream>>>(Wq, Wk, Wv, Wo, bq, bk, bv, bo,
                                                    wqkvT, woT, bcat);
  gemm_mfma_kernel<true, true><<<dim3(NQKV_ / 64, M / 128), 256, 0, stream>>>(
      x, wqkvT, bcat, qkv, M, C_, NQKV_, 576);
  attn_mfma_kernel<<<dim3(NH_, B_, 16), 256, 0, stream>>>(qkv, y);
  gemm_mfma_kernel<false, false><<<dim3(C_ / 64, M / 128), 256, 0, stream>>>(
      y, woT, bcat + NQKV_, out, M, C_, C_, 0);
}